// Round 1
// baseline (438.112 us; speedup 1.0000x reference)
//
#include <hip/hip_runtime.h>
#include <hip/hip_bf16.h>
#include <cstdint>
#include <cstddef>

#define TOK    8192
#define DMODEL 1024
#define HDIM   2048
#define MDIM   64
#define NEXP   8
#define HHALF  1024

using f32x4  = __attribute__((ext_vector_type(4))) float;
using bf16x8 = __attribute__((ext_vector_type(8))) __bf16;
using bf16x4 = __attribute__((ext_vector_type(4))) __bf16;

__global__ __launch_bounds__(256) void cvt_bf16_kernel(
    const float* __restrict__ in, __bf16* __restrict__ out, int n4) {
  int i = blockIdx.x * 256 + threadIdx.x;
  if (i >= n4) return;
  float4 v = ((const float4*)in)[i];
  bf16x4 o = { (__bf16)v.x, (__bf16)v.y, (__bf16)v.z, (__bf16)v.w };
  ((bf16x4*)out)[i] = o;
}

__global__ __launch_bounds__(256) void transpose_cvt_kernel(
    const float* __restrict__ in, __bf16* __restrict__ out, int R, int C) {
  __shared__ float t[32][33];
  size_t bo = (size_t)blockIdx.z * R * C;
  const float* inp = in + bo;
  __bf16* outp = out + bo;
  int c0 = blockIdx.x * 32, r0 = blockIdx.y * 32;
  int x = threadIdx.x & 31, y = threadIdx.x >> 5;
  #pragma unroll
  for (int i = y; i < 32; i += 8) t[i][x] = inp[(size_t)(r0 + i) * C + c0 + x];
  __syncthreads();
  #pragma unroll
  for (int i = y; i < 32; i += 8)
    outp[(size_t)(c0 + i) * R + r0 + x] = (__bf16)t[x][i];
}

// C = act(A @ Bt^T + bias); A: MxK bf16, Bt: NxK bf16, ACT 0=none 1=sigmoid
template <int BM, int BN, int OUT_BF16, int ACT>
__global__ __launch_bounds__(256) void gemm_bt(
    const __bf16* __restrict__ A, const __bf16* __restrict__ Bt,
    const float* __restrict__ bias, void* __restrict__ Cout,
    int M, int N, int K) {
  constexpr int BK = 32;
  constexpr int WM_WAVES = 2, WN_WAVES = 2;
  constexpr int WTM = BM / WM_WAVES / 16;
  constexpr int WTN = BN / WN_WAVES / 16;
  __shared__ __bf16 As[BM * BK];
  __shared__ __bf16 Bs[BN * BK];
  const int tid = threadIdx.x;
  const int wave = tid >> 6, lane = tid & 63;
  const int quad = lane >> 4, l16 = lane & 15;
  const int m0 = blockIdx.x * BM, n0 = blockIdx.y * BN;
  const int wm = (wave & (WM_WAVES - 1)) * (BM / WM_WAVES);
  const int wn = (wave / WM_WAVES) * (BN / WN_WAVES);
  f32x4 acc[WTM][WTN] = {};
  constexpr int CHA = BM * BK / 8;
  constexpr int CHB = BN * BK / 8;

  for (int k0 = 0; k0 < K; k0 += BK) {
    __syncthreads();
    #pragma unroll
    for (int c = tid; c < CHA; c += 256) {
      uint4 v = *(const uint4*)(A + (size_t)(m0 + (c >> 2)) * K + k0 + (c & 3) * 8);
      *(uint4*)(As + c * 8) = v;
    }
    #pragma unroll
    for (int c = tid; c < CHB; c += 256) {
      uint4 v = *(const uint4*)(Bt + (size_t)(n0 + (c >> 2)) * K + k0 + (c & 3) * 8);
      *(uint4*)(Bs + c * 8) = v;
    }
    __syncthreads();
    bf16x8 af[WTM], bfr[WTN];
    #pragma unroll
    for (int i = 0; i < WTM; ++i)
      af[i] = *(const bf16x8*)(As + (wm + i * 16 + l16) * BK + quad * 8);
    #pragma unroll
    for (int j = 0; j < WTN; ++j)
      bfr[j] = *(const bf16x8*)(Bs + (wn + j * 16 + l16) * BK + quad * 8);
    #pragma unroll
    for (int i = 0; i < WTM; ++i)
      #pragma unroll
      for (int j = 0; j < WTN; ++j)
        acc[i][j] = __builtin_amdgcn_mfma_f32_16x16x32_bf16(af[i], bfr[j], acc[i][j], 0, 0, 0);
  }

  #pragma unroll
  for (int i = 0; i < WTM; ++i)
    #pragma unroll
    for (int j = 0; j < WTN; ++j)
      #pragma unroll
      for (int r = 0; r < 4; ++r) {
        int m = m0 + wm + i * 16 + quad * 4 + r;
        int n = n0 + wn + j * 16 + l16;
        float v = acc[i][j][r] + bias[n];
        if (ACT == 1) v = 1.0f / (1.0f + __expf(-v));
        if (OUT_BF16)
          ((__bf16*)Cout)[(size_t)m * N + n] = (__bf16)v;
        else
          ((float*)Cout)[(size_t)m * N + n] = v;
      }
}

__global__ __launch_bounds__(256) void router_kernel(
    const float* __restrict__ cont, const float* __restrict__ rW1,
    const float* __restrict__ rb1, const float* __restrict__ rW2,
    const float* __restrict__ rb2, float* __restrict__ gates) {
  const int wave = threadIdx.x >> 6, lane = threadIdx.x & 63;
  const int n = blockIdx.x * 4 + wave;
  float c = cont[(size_t)n * 64 + lane];
  float acc = rb1[lane];
  #pragma unroll
  for (int i = 0; i < 64; ++i) {
    float ci = __shfl(c, i);
    acc = fmaf(ci, rW1[i * 64 + lane], acc);
  }
  float t = tanhf(acc);
  float logit[8];
  #pragma unroll
  for (int e = 0; e < 8; ++e) {
    float v = t * rW2[lane * 8 + e];
    #pragma unroll
    for (int o = 32; o; o >>= 1) v += __shfl_xor(v, o);
    logit[e] = v + rb2[e];
  }
  float mx = logit[0];
  #pragma unroll
  for (int e = 1; e < 8; ++e) mx = fmaxf(mx, logit[e]);
  float p[8];
  #pragma unroll
  for (int e = 0; e < 8; ++e) p[e] = __expf(logit[e] - mx);
  int e0 = 0;
  #pragma unroll
  for (int e = 1; e < 8; ++e) if (p[e] > p[e0]) e0 = e;
  int e1 = (e0 == 0) ? 1 : 0;
  #pragma unroll
  for (int e = 0; e < 8; ++e) if (e != e0 && e != e1 && p[e] > p[e1]) e1 = e;
  float wsum = p[e0] + p[e1];
  if (lane < 8) {
    float g = (lane == e0) ? p[e0] / wsum : (lane == e1) ? p[e1] / wsum : 0.0f;
    gates[(size_t)n * 8 + lane] = g;
  }
}

__global__ __launch_bounds__(256) void moe_fused_kernel(
    const float* __restrict__ cont, const __bf16* __restrict__ We1T,
    const __bf16* __restrict__ We2T, const float* __restrict__ be1,
    const float* __restrict__ be2, const float* __restrict__ gates,
    float* __restrict__ out_flat) {
  constexpr int TT = 128;
  __shared__ __bf16 cont_s[TT * 64];
  __shared__ __bf16 w1_s[64 * 64];
  __shared__ __bf16 w2_s[64 * 64];
  __shared__ __bf16 h_s[TT * 64];
  __shared__ float g_s[TT];
  const int tid = threadIdx.x;
  const int wave = tid >> 6, lane = tid & 63;
  const int quad = lane >> 4, l16 = lane & 15;
  const int t0 = blockIdx.x * TT;
  const int e = blockIdx.y;
  for (int i = tid; i < TT * 64 / 4; i += 256) {
    float4 v = *(const float4*)(cont + (size_t)t0 * 64 + i * 4);
    bf16x4 o = { (__bf16)v.x, (__bf16)v.y, (__bf16)v.z, (__bf16)v.w };
    *(bf16x4*)(cont_s + i * 4) = o;
  }
  if (tid < TT) g_s[tid] = gates[(size_t)(t0 + tid) * 8 + e];
  const int wtok = wave * 32;
  f32x4 acc2[2][4] = {};
  for (int hc = 0; hc < HHALF; hc += 64) {
    __syncthreads();
    for (int c = tid; c < 512; c += 256) {
      uint4 v = *(const uint4*)(We1T + ((size_t)e * HHALF + hc + (c >> 3)) * 64 + (c & 7) * 8);
      *(uint4*)(w1_s + c * 8) = v;
    }
    for (int c = tid; c < 512; c += 256) {
      uint4 v = *(const uint4*)(We2T + ((size_t)e * 64 + (c >> 3)) * HHALF + hc + (c & 7) * 8);
      *(uint4*)(w2_s + c * 8) = v;
    }
    __syncthreads();
    f32x4 acc1[2][4] = {};
    #pragma unroll
    for (int kk = 0; kk < 64; kk += 32) {
      bf16x8 af[2], bfr[4];
      #pragma unroll
      for (int i = 0; i < 2; ++i)
        af[i] = *(const bf16x8*)(cont_s + (wtok + i * 16 + l16) * 64 + kk + quad * 8);
      #pragma unroll
      for (int j = 0; j < 4; ++j)
        bfr[j] = *(const bf16x8*)(w1_s + (j * 16 + l16) * 64 + kk + quad * 8);
      #pragma unroll
      for (int i = 0; i < 2; ++i)
        #pragma unroll
        for (int j = 0; j < 4; ++j)
          acc1[i][j] = __builtin_amdgcn_mfma_f32_16x16x32_bf16(af[i], bfr[j], acc1[i][j], 0, 0, 0);
    }
    #pragma unroll
    for (int i = 0; i < 2; ++i)
      #pragma unroll
      for (int j = 0; j < 4; ++j)
        #pragma unroll
        for (int r = 0; r < 4; ++r) {
          int tr = wtok + i * 16 + quad * 4 + r;
          int hcol = j * 16 + l16;
          float v = acc1[i][j][r] + be1[e * HHALF + hc + hcol];
          h_s[tr * 64 + hcol] = (__bf16)fmaxf(v, 0.0f);
        }
    #pragma unroll
    for (int kk = 0; kk < 64; kk += 32) {
      bf16x8 af[2], bfr[4];
      #pragma unroll
      for (int i = 0; i < 2; ++i)
        af[i] = *(const bf16x8*)(h_s + (wtok + i * 16 + l16) * 64 + kk + quad * 8);
      #pragma unroll
      for (int j = 0; j < 4; ++j)
        bfr[j] = *(const bf16x8*)(w2_s + (j * 16 + l16) * 64 + kk + quad * 8);
      #pragma unroll
      for (int i = 0; i < 2; ++i)
        #pragma unroll
        for (int j = 0; j < 4; ++j)
          acc2[i][j] = __builtin_amdgcn_mfma_f32_16x16x32_bf16(af[i], bfr[j], acc2[i][j], 0, 0, 0);
    }
  }
  #pragma unroll
  for (int i = 0; i < 2; ++i)
    #pragma unroll
    for (int j = 0; j < 4; ++j)
      #pragma unroll
      for (int r = 0; r < 4; ++r) {
        int tr = wtok + i * 16 + quad * 4 + r;
        int m = j * 16 + l16;
        float g = g_s[tr];
        if (g != 0.0f)
          atomicAdd(out_flat + (size_t)(t0 + tr) * 64 + m,
                    g * (acc2[i][j][r] + be2[e * 64 + m]));
      }
}

__global__ __launch_bounds__(256) void ln_kernel(
    const float* __restrict__ x, const float* __restrict__ g,
    const float* __restrict__ b, float* __restrict__ out) {
  const int row = blockIdx.x;
  const float4 v = ((const float4*)(x + (size_t)row * 1024))[threadIdx.x];
  float s1 = v.x + v.y + v.z + v.w;
  float s2 = v.x * v.x + v.y * v.y + v.z * v.z + v.w * v.w;
  #pragma unroll
  for (int o = 32; o; o >>= 1) { s1 += __shfl_xor(s1, o); s2 += __shfl_xor(s2, o); }
  __shared__ float ws1[4], ws2[4];
  const int wave = threadIdx.x >> 6, lane = threadIdx.x & 63;
  if (lane == 0) { ws1[wave] = s1; ws2[wave] = s2; }
  __syncthreads();
  s1 = ws1[0] + ws1[1] + ws1[2] + ws1[3];
  s2 = ws2[0] + ws2[1] + ws2[2] + ws2[3];
  const float mu = s1 * (1.0f / 1024.0f);
  const float var = s2 * (1.0f / 1024.0f) - mu * mu;
  const float inv = rsqrtf(var + 1e-5f);
  const int col = threadIdx.x * 4;
  const float4 gv = *(const float4*)(g + col);
  const float4 bv = *(const float4*)(b + col);
  float4 o;
  o.x = (v.x - mu) * inv * gv.x + bv.x;
  o.y = (v.y - mu) * inv * gv.y + bv.y;
  o.z = (v.z - mu) * inv * gv.z + bv.z;
  o.w = (v.w - mu) * inv * gv.w + bv.w;
  *(float4*)(out + (size_t)row * 1024 + col) = o;
}

extern "C" void kernel_launch(void* const* d_in, const int* in_sizes, int n_in,
                              void* d_out, int out_size, void* d_ws, size_t ws_size,
                              hipStream_t stream) {
  const float* X     = (const float*)d_in[0];
  const float* enc_W = (const float*)d_in[1];
  const float* enc_b = (const float*)d_in[2];
  const float* s2c_W = (const float*)d_in[3];
  const float* s2c_b = (const float*)d_in[4];
  const float* rW1   = (const float*)d_in[5];
  const float* rb1   = (const float*)d_in[6];
  const float* rW2   = (const float*)d_in[7];
  const float* rb2   = (const float*)d_in[8];
  const float* We1   = (const float*)d_in[9];
  const float* be1   = (const float*)d_in[10];
  const float* We2   = (const float*)d_in[11];
  const float* be2   = (const float*)d_in[12];
  const float* c2s_W = (const float*)d_in[13];
  const float* c2s_b = (const float*)d_in[14];
  const float* dec_W = (const float*)d_in[15];
  const float* dec_b = (const float*)d_in[16];
  const float* ln_g  = (const float*)d_in[17];
  const float* ln_b  = (const float*)d_in[18];
  float* out = (float*)d_out;

  char* ws = (char*)d_ws;
  size_t off = 0;
  auto alloc = [&](size_t bytes) -> void* {
    void* p = ws + off;
    off = (off + bytes + 255) & ~(size_t)255;
    return p;
  };
  __bf16* Xb        = (__bf16*)alloc((size_t)TOK * DMODEL * 2);
  __bf16* encWT     = (__bf16*)alloc((size_t)HDIM * DMODEL * 2);
  __bf16* spikesEnc = (__bf16*)alloc((size_t)TOK * HDIM * 2);
  __bf16* s2cWT     = (__bf16*)alloc((size_t)MDIM * HDIM * 2);
  float*  cont      = (float*)alloc((size_t)TOK * MDIM * 4);
  float*  gates     = (float*)alloc((size_t)TOK * NEXP * 4);
  __bf16* We1T      = (__bf16*)alloc((size_t)NEXP * HHALF * MDIM * 2);
  __bf16* We2T      = (__bf16*)alloc((size_t)NEXP * MDIM * HHALF * 2);
  float*  outFlat   = (float*)alloc((size_t)TOK * MDIM * 4);
  __bf16* outFlatB  = (__bf16*)alloc((size_t)TOK * MDIM * 2);
  __bf16* c2sWT     = (__bf16*)alloc((size_t)HDIM * MDIM * 2);
  __bf16* spikesMoe = (__bf16*)alloc((size_t)TOK * HDIM * 2);
  __bf16* decWT     = (__bf16*)alloc((size_t)DMODEL * HDIM * 2);
  float*  decoded   = (float*)spikesEnc;  // alias: spikesEnc dead after GEMM2

  cvt_bf16_kernel<<<TOK * DMODEL / 4 / 256, 256, 0, stream>>>(X, Xb, TOK * DMODEL / 4);
  transpose_cvt_kernel<<<dim3(HDIM / 32, DMODEL / 32, 1), 256, 0, stream>>>(enc_W, encWT, DMODEL, HDIM);
  transpose_cvt_kernel<<<dim3(MDIM / 32, HDIM / 32, 1), 256, 0, stream>>>(s2c_W, s2cWT, HDIM, MDIM);
  transpose_cvt_kernel<<<dim3(HDIM / 32, MDIM / 32, 1), 256, 0, stream>>>(c2s_W, c2sWT, MDIM, HDIM);
  transpose_cvt_kernel<<<dim3(DMODEL / 32, HDIM / 32, 1), 256, 0, stream>>>(dec_W, decWT, HDIM, DMODEL);
  transpose_cvt_kernel<<<dim3(HHALF / 32, MDIM / 32, NEXP), 256, 0, stream>>>(We1, We1T, MDIM, HHALF);
  transpose_cvt_kernel<<<dim3(MDIM / 32, HHALF / 32, NEXP), 256, 0, stream>>>(We2, We2T, HHALF, MDIM);

  gemm_bt<128, 128, 1, 1><<<dim3(TOK / 128, HDIM / 128), 256, 0, stream>>>(
      Xb, encWT, enc_b, spikesEnc, TOK, HDIM, DMODEL);
  gemm_bt<64, 64, 0, 0><<<dim3(TOK / 64, 1), 256, 0, stream>>>(
      spikesEnc, s2cWT, s2c_b, cont, TOK, MDIM, HDIM);
  router_kernel<<<TOK / 4, 256, 0, stream>>>(cont, rW1, rb1, rW2, rb2, gates);
  hipMemsetAsync(outFlat, 0, (size_t)TOK * MDIM * 4, stream);
  moe_fused_kernel<<<dim3(TOK / 128, NEXP), 256, 0, stream>>>(
      cont, We1T, We2T, be1, be2, gates, outFlat);
  cvt_bf16_kernel<<<TOK * MDIM / 4 / 256, 256, 0, stream>>>(outFlat, outFlatB, TOK * MDIM / 4);
  gemm_bt<128, 128, 1, 1><<<dim3(TOK / 128, HDIM / 128), 256, 0, stream>>>(
      outFlatB, c2sWT, c2s_b, spikesMoe, TOK, HDIM, MDIM);
  gemm_bt<128, 128, 0, 1><<<dim3(TOK / 128, DMODEL / 128), 256, 0, stream>>>(
      spikesMoe, decWT, dec_b, decoded, TOK, DMODEL, HDIM);
  ln_kernel<<<TOK, 256, 0, stream>>>(decoded, ln_g, ln_b, out);
}